// Round 4
// baseline (401.102 us; speedup 1.0000x reference)
//
#include <hip/hip_runtime.h>
#include <math.h>

#define BHX 32
#define NN 4096
#define DD 64
#define MM 266
#define MP 272
#define NORMZ 0.35355339059327379f   // 64^-0.25
#define RATIO 0.06131393394849658f   // 266^-0.5
#define EPSV 1e-4f
#define NEG_INF (-3.4e38f)
#define LSTR 72                       // LDS row stride in ushorts (144B, 16B aligned)
#define GSTR 320                      // gctxT row stride in ushorts

typedef __attribute__((ext_vector_type(8))) short bfrag;
typedef __attribute__((ext_vector_type(4))) float f32x4;

#define MFMA(a, b, c) __builtin_amdgcn_mfma_f32_16x16x32_bf16((a), (b), (c), 0, 0, 0)

__device__ inline ushort bf16rne(float x) {
    union { float f; unsigned u; } c; c.f = x;
    unsigned r = c.u + 0x7FFFu + ((c.u >> 16) & 1u);
    return (ushort)(r >> 16);
}
__device__ inline float bf2f(ushort h) {
    union { unsigned u; float f; } c; c.u = ((unsigned)h) << 16;
    return c.f;
}
__device__ inline void splitf(float x, ushort& h, ushort& l) {
    h = bf16rne(x);
    l = bf16rne(x - bf2f(h));
}

// ---------------------------------------------------------------------------
// proj split: proj fp32 [266][64] -> pH/pL bf16 [272][64] (rows >=266 zero)
// ---------------------------------------------------------------------------
__global__ void proj_split(const float* __restrict__ proj,
                           ushort* __restrict__ pH, ushort* __restrict__ pL)
{
    int i = (blockIdx.x * 256 + threadIdx.x) * 4;   // 17*256*4 = 17408 = 272*64
    int m = i >> 6;
    float4 x = (m < MM) ? *(const float4*)(proj + i) : make_float4(0.f, 0.f, 0.f, 0.f);
    ushort h0, l0, h1, l1, h2, l2, h3, l3;
    splitf(x.x, h0, l0); splitf(x.y, h1, l1); splitf(x.z, h2, l2); splitf(x.w, h3, l3);
    *(ushort4*)(pH + i) = make_ushort4(h0, h1, h2, h3);
    *(ushort4*)(pL + i) = make_ushort4(l0, l1, l2, l3);
}

// ===========================================================================
// k-pass: per 64-row subtile: dd = (NORMZ*k)@proj^T (split-bf16 MFMA, 32-m
// chunks), u = exp(dd - diag), block dd-max, ctx partial += u^T@v via MFMA,
// kc partial += colsum(u), vsum partial += colsum(v).
// grid (npart, 32 heads), block 256, 3 blocks/CU.
// ===========================================================================
__launch_bounds__(256, 3)
__global__ void kpass(const float* __restrict__ kin, const float* __restrict__ vin,
                      const ushort* __restrict__ pjH, const ushort* __restrict__ pjL,
                      float* __restrict__ ctxP, float* __restrict__ kcP,
                      float* __restrict__ pmax, float* __restrict__ vsumg)
{
    __shared__ __align__(16) ushort uH[64 * LSTR], uLo[64 * LSTR];   // dataA, then uT
    __shared__ __align__(16) ushort vH[64 * LSTR], vLo[64 * LSTR];   // vT [e][n]
    __shared__ __align__(16) ushort rpH[32 * LSTR], rpL[32 * LSTR];  // proj chunk
    __shared__ float diagS[64];
    __shared__ float kcS[MP];
    __shared__ float redS[4];

    const int t = threadIdx.x;
    const int w = t >> 6;
    const int lane = t & 63;
    const int l15 = lane & 15;
    const int q = lane >> 4;
    const int hd = blockIdx.y, nb = blockIdx.x;
    const int npart = gridDim.x;
    const int nsub = (NN / npart) >> 6;    // 2 (npart=32) or 4 (npart=16)

    if (t < 256) kcS[t] = 0.f;
    if (t < 16) kcS[256 + t] = 0.f;

    const f32x4 zf = {0.f, 0.f, 0.f, 0.f};
    f32x4 cacc[8][2];
    f32x4 cacc8 = zf;
    #pragma unroll
    for (int c = 0; c < 8; ++c)
        #pragma unroll
        for (int je = 0; je < 2; ++je) cacc[c][je] = zf;
    float bmaxl = NEG_INF;
    float vsAcc = 0.f;

    #pragma unroll 1
    for (int st = 0; st < nsub; ++st) {
        const int n0 = nb * (nsub << 6) + (st << 6);
        __syncthreads();   // protect restage vs prior chunk's LDS readers

        // ---- stage dataA (split, +diag) ----
        const float* kb = kin + ((size_t)hd * NN + n0) * DD;
        #pragma unroll
        for (int j = 0; j < 4; ++j) {
            int i = (t + (j << 8)) << 2;
            int r = i >> 6, cc = i & 63;
            float4 x = *(const float4*)(kb + i);
            float x0 = x.x * NORMZ, x1 = x.y * NORMZ, x2 = x.z * NORMZ, x3 = x.w * NORMZ;
            ushort h0, l0, h1, l1, h2, l2, h3, l3;
            splitf(x0, h0, l0); splitf(x1, h1, l1); splitf(x2, h2, l2); splitf(x3, h3, l3);
            *(ushort4*)&uH[r * LSTR + cc] = make_ushort4(h0, h1, h2, h3);
            *(ushort4*)&uLo[r * LSTR + cc] = make_ushort4(l0, l1, l2, l3);
            float ss = x0 * x0 + x1 * x1 + x2 * x2 + x3 * x3;
            #pragma unroll
            for (int d = 1; d < 16; d <<= 1) ss += __shfl_xor(ss, d);
            if (l15 == 0) diagS[r] = 0.5f * ss;
        }
        // ---- stage vT (wave-coalesced row loads, conflict-free ushort4 writes) ----
        const float* vb = vin + ((size_t)hd * NN + n0) * DD;
        {
            const int ve = lane;    // e = lane; wave w covers n-quads w, w+4, w+8, w+12
            #pragma unroll
            for (int jj = 0; jj < 4; ++jj) {
                const int nq = w + (jj << 2);
                float x0 = vb[((nq << 2) + 0) * DD + ve];
                float x1 = vb[((nq << 2) + 1) * DD + ve];
                float x2 = vb[((nq << 2) + 2) * DD + ve];
                float x3 = vb[((nq << 2) + 3) * DD + ve];
                vsAcc += x0 + x1 + x2 + x3;
                ushort h0, l0, h1, l1, h2, l2, h3, l3;
                splitf(x0, h0, l0); splitf(x1, h1, l1);
                splitf(x2, h2, l2); splitf(x3, h3, l3);
                *(ushort4*)&vH[ve * LSTR + (nq << 2)] = make_ushort4(h0, h1, h2, h3);
                *(ushort4*)&vLo[ve * LSTR + (nq << 2)] = make_ushort4(l0, l1, l2, l3);
            }
        }
        __syncthreads();

        // dataA fragments (kept in regs; uH region becomes uT after)
        bfrag aH[2], aL[2];
        {
            const int row = (w << 4) + l15;
            aH[0] = *(const bfrag*)&uH[row * LSTR + (q << 3)];
            aH[1] = *(const bfrag*)&uH[row * LSTR + 32 + (q << 3)];
            aL[0] = *(const bfrag*)&uLo[row * LSTR + (q << 3)];
            aL[1] = *(const bfrag*)&uLo[row * LSTR + 32 + (q << 3)];
        }

        #pragma unroll
        for (int c = 0; c < 9; ++c) {
            const int mtiles = (c < 8) ? 2 : 1;
            const int m0 = c << 5;
            // stage proj chunk
            {
                const int tot8 = mtiles << 7;
                for (int idx = t; idx < tot8; idx += 256) {
                    int i = idx << 3; int r = i >> 6, cc = i & 63;
                    *(uint4*)&rpH[r * LSTR + cc] = *(const uint4*)(pjH + ((m0 + r) << 6) + cc);
                    *(uint4*)&rpL[r * LSTR + cc] = *(const uint4*)(pjL + ((m0 + r) << 6) + cc);
                }
            }
            __syncthreads();   // B1: proj ready; prior ctx readers of uT done

            // dd MFMAs (a=data -> D rows = n, D cols (l15) = m)
            f32x4 dd4[2];
            #pragma unroll
            for (int mt = 0; mt < 2; ++mt) {
                if (mt >= mtiles) break;
                const int mrow = (mt << 4) + l15;
                bfrag bH0 = *(const bfrag*)&rpH[mrow * LSTR + (q << 3)];
                bfrag bH1 = *(const bfrag*)&rpH[mrow * LSTR + 32 + (q << 3)];
                bfrag bL0 = *(const bfrag*)&rpL[mrow * LSTR + (q << 3)];
                bfrag bL1 = *(const bfrag*)&rpL[mrow * LSTR + 32 + (q << 3)];
                f32x4 a = zf;
                a = MFMA(aH[0], bL0, a);
                a = MFMA(aH[1], bL1, a);
                a = MFMA(aL[0], bH0, a);
                a = MFMA(aL[1], bH1, a);
                a = MFMA(aH[0], bH0, a);
                a = MFMA(aH[1], bH1, a);
                dd4[mt] = a;
            }
            // exp + max + kc + ushort4 scatter into uT (rows m, cols n)
            #pragma unroll
            for (int mt = 0; mt < 2; ++mt) {
                if (mt >= mtiles) break;
                const int mg = m0 + (mt << 4) + l15;
                const bool valid = (mg < MM);
                ushort uh[4], ul[4];
                float csum = 0.f;
                #pragma unroll
                for (int reg = 0; reg < 4; ++reg) {
                    float dv = dd4[mt][reg];
                    float u = 0.f;
                    if (valid) {
                        bmaxl = fmaxf(bmaxl, dv);
                        u = __expf(dv - diagS[(w << 4) + (q << 2) + reg]);
                    }
                    csum += u;
                    splitf(u, uh[reg], ul[reg]);
                }
                *(ushort4*)&uH[((mt << 4) + l15) * LSTR + (w << 4) + (q << 2)] =
                    make_ushort4(uh[0], uh[1], uh[2], uh[3]);
                *(ushort4*)&uLo[((mt << 4) + l15) * LSTR + (w << 4) + (q << 2)] =
                    make_ushort4(ul[0], ul[1], ul[2], ul[3]);
                csum += __shfl_xor(csum, 16);
                csum += __shfl_xor(csum, 32);
                if (q == 0) atomicAdd(&kcS[mg], csum);
            }
            __syncthreads();   // B2: uT complete

            // ctx MFMAs: D[m rows][e cols] += uT . vT
            if (c < 8) {
                const int tw = w & 1, eh0 = (w >> 1) << 1;
                const int urow = (tw << 4) + l15;
                bfrag uH0 = *(const bfrag*)&uH[urow * LSTR + (q << 3)];
                bfrag uH1 = *(const bfrag*)&uH[urow * LSTR + 32 + (q << 3)];
                bfrag uL0 = *(const bfrag*)&uLo[urow * LSTR + (q << 3)];
                bfrag uL1 = *(const bfrag*)&uLo[urow * LSTR + 32 + (q << 3)];
                #pragma unroll
                for (int je = 0; je < 2; ++je) {
                    const int erow = ((eh0 + je) << 4) + l15;
                    bfrag vH0 = *(const bfrag*)&vH[erow * LSTR + (q << 3)];
                    bfrag vH1 = *(const bfrag*)&vH[erow * LSTR + 32 + (q << 3)];
                    bfrag vL0 = *(const bfrag*)&vLo[erow * LSTR + (q << 3)];
                    bfrag vL1 = *(const bfrag*)&vLo[erow * LSTR + 32 + (q << 3)];
                    f32x4 a = cacc[c][je];
                    a = MFMA(uH0, vL0, a);
                    a = MFMA(uH1, vL1, a);
                    a = MFMA(uL0, vH0, a);
                    a = MFMA(uL1, vH1, a);
                    a = MFMA(uH0, vH0, a);
                    a = MFMA(uH1, vH1, a);
                    cacc[c][je] = a;
                }
            } else {
                const int urow = l15;
                bfrag uH0 = *(const bfrag*)&uH[urow * LSTR + (q << 3)];
                bfrag uH1 = *(const bfrag*)&uH[urow * LSTR + 32 + (q << 3)];
                bfrag uL0 = *(const bfrag*)&uLo[urow * LSTR + (q << 3)];
                bfrag uL1 = *(const bfrag*)&uLo[urow * LSTR + 32 + (q << 3)];
                const int erow = (w << 4) + l15;
                bfrag vH0 = *(const bfrag*)&vH[erow * LSTR + (q << 3)];
                bfrag vH1 = *(const bfrag*)&vH[erow * LSTR + 32 + (q << 3)];
                bfrag vL0 = *(const bfrag*)&vLo[erow * LSTR + (q << 3)];
                bfrag vL1 = *(const bfrag*)&vLo[erow * LSTR + 32 + (q << 3)];
                f32x4 a = cacc8;
                a = MFMA(uH0, vL0, a);
                a = MFMA(uH1, vL1, a);
                a = MFMA(uL0, vH0, a);
                a = MFMA(uL1, vH1, a);
                a = MFMA(uH0, vH0, a);
                a = MFMA(uH1, vH1, a);
                cacc8 = a;
            }
        }
    }

    // ---- epilogue ----
    __syncthreads();
    float* fsc = (float*)uH;     // data/uT region dead -> float scratch
    fsc[t] = vsAcc;
    {
        float bm = bmaxl;
        #pragma unroll
        for (int d = 1; d < 64; d <<= 1) bm = fmaxf(bm, __shfl_xor(bm, d));
        if (lane == 0) redS[w] = bm;
    }
    __syncthreads();
    if (t < 64) atomicAdd(&vsumg[hd * DD + t],
                          fsc[t] + fsc[t + 64] + fsc[t + 128] + fsc[t + 192]);
    if (t == 0) pmax[hd * npart + nb] =
        fmaxf(fmaxf(redS[0], redS[1]), fmaxf(redS[2], redS[3]));
    for (int m = t; m < MP; m += 256) kcP[(size_t)(hd * npart + nb) * MP + m] = kcS[m];

    float* cp = ctxP + (size_t)(hd * npart + nb) * MP * DD;
    #pragma unroll
    for (int c = 0; c < 8; ++c) {
        const int mbase = (c << 5) + ((w & 1) << 4) + (q << 2);
        #pragma unroll
        for (int je = 0; je < 2; ++je) {
            const int ecol = ((((w >> 1) << 1) + je) << 4) + l15;
            #pragma unroll
            for (int reg = 0; reg < 4; ++reg)
                cp[(mbase + reg) * DD + ecol] = cacc[c][je][reg];
        }
    }
    #pragma unroll
    for (int reg = 0; reg < 4; ++reg)
        cp[(256 + (q << 2) + reg) * DD + (w << 4) + l15] = cacc8[reg];
}

// ===========================================================================
// ctx reduce (+inline stab reduction): sum npart partials, scale by
// Asc=RATIO*e^-stab, add REPS*vsum, split bf16, write TRANSPOSED
// gctxT[hd][e][m] (row 64 = kcF, rows 65..79 stay zero).  grid (17, 32).
// ===========================================================================
__global__ void ctx_reduce(const float* __restrict__ ctxP, const float* __restrict__ kcP,
                           const float* __restrict__ vsum, const float* __restrict__ pmax,
                           ushort* __restrict__ gH, ushort* __restrict__ gL, int npart)
{
    __shared__ float smx[256];
    __shared__ ushort hiT[64][20], loT[64][20];
    const int t = threadIdx.x, mt = blockIdx.x, hd = blockIdx.y;

    float mx = NEG_INF;
    for (int i = t; i < npart * 32; i += 256) mx = fmaxf(mx, pmax[i]);
    smx[t] = mx;
    __syncthreads();
    for (int s = 128; s > 0; s >>= 1) {
        if (t < s) smx[t] = fmaxf(smx[t], smx[t + s]);
        __syncthreads();
    }
    const float Asc = RATIO * __expf(-smx[0]);
    const float REPS = RATIO * EPSV;

    const int e = t & 63, mq = t >> 6;
    const float vs = vsum[hd * DD + e];
    #pragma unroll
    for (int i = 0; i < 4; ++i) {
        const int ml = (mq << 2) + i;
        const int m = (mt << 4) + ml;
        float s = 0.f;
        for (int nbk = 0; nbk < npart; ++nbk)
            s += ctxP[((size_t)(hd * npart + nbk) * MP + m) * DD + e];
        float val = Asc * s + REPS * vs;
        ushort h, l; splitf(val, h, l);
        hiT[e][ml] = h; loT[e][ml] = l;
    }
    __syncthreads();
    {
        const int i = t << 2, e2 = i >> 4, cc = i & 15;
        ushort4 hv = make_ushort4(hiT[e2][cc], hiT[e2][cc + 1], hiT[e2][cc + 2], hiT[e2][cc + 3]);
        ushort4 lv = make_ushort4(loT[e2][cc], loT[e2][cc + 1], loT[e2][cc + 2], loT[e2][cc + 3]);
        *(ushort4*)(gH + ((size_t)hd * 80 + e2) * GSTR + mt * 16 + cc) = hv;
        *(ushort4*)(gL + ((size_t)hd * 80 + e2) * GSTR + mt * 16 + cc) = lv;
    }
    if (t < 16) {
        const int m = mt * 16 + t;
        float s = 0.f;
        for (int nbk = 0; nbk < npart; ++nbk) s += kcP[(size_t)(hd * npart + nbk) * MP + m];
        float val = Asc * s + ((m < MM) ? REPS * (float)NN : 0.f);
        ushort h, l; splitf(val, h, l);
        gH[((size_t)hd * 80 + 64) * GSTR + m] = h;
        gL[((size_t)hd * 80 + 64) * GSTR + m] = l;
    }
}

// ===========================================================================
// q-pass: dd via MFMA with SWAPPED operands (proj=A -> lane regs = m,
// l15 = n), per-lane scalar rowmax/diag, qp in regs; out = qp@ctxT via MFMA
// with denominator as column e=64.  LDS union: region1 = dataA -> qpA,
// region2 = proj chunk -> ctxT chunk.  grid (64, 32), 3 blocks/CU.
// ===========================================================================
__launch_bounds__(256, 3)
__global__ void qpass(const float* __restrict__ qin,
                      const ushort* __restrict__ pjH, const ushort* __restrict__ pjL,
                      const ushort* __restrict__ gH, const ushort* __restrict__ gL,
                      float* __restrict__ outp)
{
    __shared__ __align__(16) ushort r1H[64 * LSTR], r1L[64 * LSTR];  // dataA, then qpA
    __shared__ __align__(16) ushort r2H[80 * LSTR], r2L[80 * LSTR];  // proj, then ctxT
    __shared__ float diagS[64];

    const int t = threadIdx.x;
    const int w = t >> 6;
    const int lane = t & 63;
    const int l15 = lane & 15;
    const int q = lane >> 4;
    const int hd = blockIdx.y;
    const int n0 = blockIdx.x << 6;

    // ---- stage dataA (split, +diag) ----
    const float* qb = qin + ((size_t)hd * NN + n0) * DD;
    #pragma unroll
    for (int j = 0; j < 4; ++j) {
        int i = (t + (j << 8)) << 2;
        int r = i >> 6, cc = i & 63;
        float4 x = *(const float4*)(qb + i);
        float x0 = x.x * NORMZ, x1 = x.y * NORMZ, x2 = x.z * NORMZ, x3 = x.w * NORMZ;
        ushort h0, l0, h1, l1, h2, l2, h3, l3;
        splitf(x0, h0, l0); splitf(x1, h1, l1); splitf(x2, h2, l2); splitf(x3, h3, l3);
        *(ushort4*)&r1H[r * LSTR + cc] = make_ushort4(h0, h1, h2, h3);
        *(ushort4*)&r1L[r * LSTR + cc] = make_ushort4(l0, l1, l2, l3);
        float ss = x0 * x0 + x1 * x1 + x2 * x2 + x3 * x3;
        #pragma unroll
        for (int d = 1; d < 16; d <<= 1) ss += __shfl_xor(ss, d);
        if (l15 == 0) diagS[r] = 0.5f * ss;
    }
    __syncthreads();

    // data fragments (B operand), held in regs; r1 region is dead after this
    bfrag dH0, dH1, dL0, dL1;
    {
        const int row = (w << 4) + l15;
        dH0 = *(const bfrag*)&r1H[row * LSTR + (q << 3)];
        dH1 = *(const bfrag*)&r1H[row * LSTR + 32 + (q << 3)];
        dL0 = *(const bfrag*)&r1L[row * LSTR + (q << 3)];
        dL1 = *(const bfrag*)&r1L[row * LSTR + 32 + (q << 3)];
    }
    const float dg = diagS[(w << 4) + l15];   // this lane's n-row diag

    const f32x4 zf = {0.f, 0.f, 0.f, 0.f};
    f32x4 ddq[17];

    // ---- phase 1: dd for all 272 m (D rows = m via proj-as-A) ----
    #pragma unroll
    for (int c = 0; c < 5; ++c) {
        const int mtiles = (c < 4) ? 4 : 1;
        const int m0 = c << 6;
        __syncthreads();   // protect r2 restage vs prior frag readers
        {
            const int tot8 = mtiles << 7;
            for (int idx = t; idx < tot8; idx += 256) {
                int i = idx << 3; int r = i >> 6, cc = i & 63;
                *(uint4*)&r2H[r * LSTR + cc] = *(const uint4*)(pjH + ((m0 + r) << 6) + cc);
                *(uint4*)&r2L[r * LSTR + cc] = *(const uint4*)(pjL + ((m0 + r) << 6) + cc);
            }
        }
        __syncthreads();
        #pragma unroll
        for (int mt = 0; mt < 4; ++mt) {
            if (mt >= mtiles) break;
            const int mrow = (mt << 4) + l15;
            bfrag pH0 = *(const bfrag*)&r2H[mrow * LSTR + (q << 3)];
            bfrag pH1 = *(const bfrag*)&r2H[mrow * LSTR + 32 + (q << 3)];
            bfrag pL0 = *(const bfrag*)&r2L[mrow * LSTR + (q << 3)];
            bfrag pL1 = *(const bfrag*)&r2L[mrow * LSTR + 32 + (q << 3)];
            f32x4 a = zf;
            a = MFMA(pH0, dL0, a);
            a = MFMA(pH1, dL1, a);
            a = MFMA(pL0, dH0, a);
            a = MFMA(pL1, dH1, a);
            a = MFMA(pH0, dH0, a);
            a = MFMA(pH1, dH1, a);
            ddq[(c << 2) + mt] = a;
        }
    }

    // ---- phase 2: scalar rowmax + qp (regs only; lane regs = m, lane = n) ----
    {
        float mx = NEG_INF;
        #pragma unroll
        for (int ti = 0; ti < 17; ++ti) {
            #pragma unroll
            for (int reg = 0; reg < 4; ++reg) {
                bool valid = (ti < 16) || ((q << 2) + reg < 10);
                if (valid) mx = fmaxf(mx, ddq[ti][reg]);
            }
        }
        mx = fmaxf(mx, __shfl_xor(mx, 16));
        mx = fmaxf(mx, __shfl_xor(mx, 32));
        const float sub = dg + mx;
        #pragma unroll
        for (int ti = 0; ti < 17; ++ti) {
            #pragma unroll
            for (int reg = 0; reg < 4; ++reg) {
                bool valid = (ti < 16) || ((q << 2) + reg < 10);
                ddq[ti][reg] = valid ? (RATIO * (__expf(ddq[ti][reg] - sub) + EPSV)) : 0.f;
            }
        }
    }

    // ---- phase 3: out = qp @ ctxT (denominator = col e=64) ----
    f32x4 oacc[5];
    #pragma unroll
    for (int et = 0; et < 5; ++et) oacc[et] = zf;

    #pragma unroll
    for (int c = 0; c < 5; ++c) {
        const int mtiles = (c < 4) ? 4 : 1;
        __syncthreads();   // prior readers of r1/r2 done
        // stage ctxT chunk [80 e][64 m] into r2
        for (int idx = t; idx < 640; idx += 256) {
            int i = idx << 3; int e = i >> 6, mm = i & 63;
            *(uint4*)&r2H[e * LSTR + mm] =
                *(const uint4*)(gH + ((size_t)hd * 80 + e) * GSTR + (c << 6) + mm);
            *(uint4*)&r2L[e * LSTR + mm] =
                *(const uint4*)(gL + ((size_t)hd * 80 + e) * GSTR + (c << 6) + mm);
        }
        // scatter qpA into r1 (ushort4 row-writes: row n = w*16+l15, cols m)
        #pragma unroll
        for (int mt = 0; mt < 4; ++mt) {
            if (mt >= mtiles) break;
            ushort h0, l0, h1, l1, h2, l2, h3, l3;
            f32x4 v = ddq[(c << 2) + mt];
            splitf(v[0], h0, l0); splitf(v[1], h1, l1);
            splitf(v[2], h2, l2); splitf(v[3], h3, l3);
            *(ushort4*)&r1H[((w << 4) + l15) * LSTR + (mt << 4) + (q << 2)] =
                make_ushort4(h0, h1, h2, h3);
            *(ushort4*)&r1L[((w << 4) + l15) * LSTR + (mt << 4) + (q << 2)] =
                make_ushort4(l0, l1, l2, l3);
        }
        if (c == 4) {   // zero K-padding cols 16..31
            *(ushort4*)&r1H[((w << 4) + l15) * LSTR + 16 + (q << 2)] = make_ushort4(0, 0, 0, 0);
            *(ushort4*)&r1L[((w << 4) + l15) * LSTR + 16 + (q << 2)] = make_ushort4(0, 0, 0, 0);
        }
        __syncthreads();
        // MFMAs: A = qpA (rows n), B = ctxT (rows e)
        const int arow = (w << 4) + l15;
        bfrag aH0 = *(const bfrag*)&r1H[arow * LSTR + (q << 3)];
        bfrag aL0 = *(const bfrag*)&r1L[arow * LSTR + (q << 3)];
        bfrag aH1, aL1;
        if (c < 4) {
            aH1 = *(const bfrag*)&r1H[arow * LSTR + 32 + (q << 3)];
            aL1 = *(const bfrag*)&r1L[arow * LSTR + 32 + (q << 3)];
        }
        #pragma unroll
        for (int et = 0; et < 5; ++et) {
            const int erow = (et << 4) + l15;
            bfrag cH0 = *(const bfrag*)&r2H[erow * LSTR + (q << 3)];
            bfrag cL0 = *(const bfrag*)&r2L[erow * LSTR + (q << 3)];
            f32x4 a = oacc[et];
            a = MFMA(aH0, cL0, a);
            a = MFMA(aL0, cH0, a);
            a = MFMA(aH0, cH0, a);
            if (c < 4) {
                bfrag cH1 = *(const bfrag*)&r2H[erow * LSTR + 32 + (q << 3)];
                bfrag cL1 = *(const bfrag*)&r2L[erow * LSTR + 32 + (q << 3)];
                a = MFMA(aH1, cL1, a);
                a = MFMA(aL1, cH1, a);
                a = MFMA(aH1, cH1, a);
            }
            oacc[et] = a;
        }
    }

    // ---- epilogue: divide by denominator (col e=64 -> et=4, l15==0) ----
    float dinv[4];
    #pragma unroll
    for (int reg = 0; reg < 4; ++reg) {
        float den = __shfl(oacc[4][reg], lane & 48);
        dinv[reg] = 1.f / den;
    }
    float* ob = outp + ((size_t)hd * NN + n0) * DD;
    #pragma unroll
    for (int et = 0; et < 4; ++et)
        #pragma unroll
        for (int reg = 0; reg < 4; ++reg)
            ob[((w << 4) + (q << 2) + reg) * DD + (et << 4) + l15] = oacc[et][reg] * dinv[reg];
}

// ---------------------------------------------------------------------------
extern "C" void kernel_launch(void* const* d_in, const int* in_sizes, int n_in,
                              void* d_out, int out_size, void* d_ws, size_t ws_size,
                              hipStream_t stream)
{
    (void)in_sizes; (void)n_in; (void)out_size;
    const float* q = (const float*)d_in[0];
    const float* k = (const float*)d_in[1];
    const float* v = (const float*)d_in[2];
    const float* proj = (const float*)d_in[3];
    float* out = (float*)d_out;
    char* ws = (char*)d_ws;

    ushort* gH = (ushort*)(ws);                        // 1,638,400 B
    ushort* gL = (ushort*)(ws + 1638400);              // 1,638,400 B
    float* vsm = (float*)(ws + 3276800);               // 8,192 B
    ushort* pH = (ushort*)(ws + 3284992);              // 34,816 B
    ushort* pL = (ushort*)(ws + 3319808);              // 34,816 B
    const size_t base = 3354624;

    // npart = 32 (128-row kpass blocks, 3/CU-friendly grid) if ws allows, else 16
    const size_t need32 = base + (size_t)32 * 32 * MP * DD * 4
                               + (size_t)32 * 32 * MP * 4 + (size_t)32 * 32 * 4;
    const int npart = (ws_size >= need32) ? 32 : 16;

    float* ctxP = (float*)(ws + base);
    float* kcP  = ctxP + (size_t)npart * 32 * MP * DD;
    float* pmax = kcP + (size_t)npart * 32 * MP;

    hipMemsetAsync(ws, 0, 3284992, stream);            // gH, gL, vsum

    proj_split<<<dim3(17), 256, 0, stream>>>(proj, pH, pL);
    kpass<<<dim3(npart, 32), 256, 0, stream>>>(k, v, pH, pL, ctxP, kcP, pmax, vsm);
    ctx_reduce<<<dim3(17, 32), 256, 0, stream>>>(ctxP, kcP, vsm, pmax, gH, gL, npart);
    qpass<<<dim3(64, 32), 256, 0, stream>>>(q, pH, pL, gH, gL, out);
}